// Round 1
// baseline (1360.530 us; speedup 1.0000x reference)
//
#include <hip/hip_runtime.h>

#define BB 32
#define TT 8
#define NN 1024
#define KNN 20
#define HH 64
#define CLS 14

__device__ __constant__ float kEPS = 1e-5f;

// ---------------------------------------------------------------------------
// Kernel A: per (t, b, 64-point chunk). One wave handles 16 query points.
// For each query point: distances to all 1024 xyz2 points (16 per lane, in
// registers), 20 iterations of wave-wide argmin (jax top_k tie semantics:
// smallest distance, then smallest index), then EdgeConv MLP with lane =
// output channel, per-edge clamp at 0, max-reduce into acc via uint atomicMax.
// acc layout: acc[b*448 + t*64 + j]   (t = 0..6 corresponds to timestep i=t+1)
// ---------------------------------------------------------------------------
__global__ __launch_bounds__(256) void knn_edge_kernel(
    const float* __restrict__ x,    // [B,T,N,3]
    const float* __restrict__ W1,   // [6,H]
    const float* __restrict__ b1,   // [H]
    const float* __restrict__ g1,   // [H]
    const float* __restrict__ be1,  // [H]
    float* __restrict__ acc)        // [B, 7*H], zero-initialized
{
    __shared__ float x2x[NN], x2y[NN], x2z[NN], s2[NN];
    __shared__ unsigned smax[HH];

    const int chunk = blockIdx.x;   // 0..15
    const int b     = blockIdx.y;   // 0..31
    const int t     = blockIdx.z;   // 0..6: xyz2 = x[:,t], xyz1 = x[:,t+1]

    const int tid  = threadIdx.x;
    const int lane = tid & 63;
    const int wave = tid >> 6;

    // stage xyz2[b] and its squared norms
    for (int i = tid; i < NN; i += 256) {
        const float* p = x + (((size_t)b * TT + t) * NN + i) * 3;
        const float px = p[0], py = p[1], pz = p[2];
        x2x[i] = px; x2y[i] = py; x2z[i] = pz;
        s2[i] = px * px + py * py + pz * pz;
    }
    if (tid < HH) smax[tid] = 0u;
    __syncthreads();

    // per-lane (= per-channel) MLP constants
    const float w0 = W1[0 * HH + lane], w1 = W1[1 * HH + lane],
                w2 = W1[2 * HH + lane], w3 = W1[3 * HH + lane],
                w4 = W1[4 * HH + lane], w5 = W1[5 * HH + lane];
    const float b1l   = b1[lane];
    const float scale = g1[lane] / sqrtf(1.0f + kEPS);
    const float be1l  = be1[lane];

    const float INFD = 3.0e38f;
    float cmax = 0.0f;   // final clamp-at-0 folded in

    const int n0 = chunk * 64 + wave * 16;
    for (int p = 0; p < 16; ++p) {
        const int n = n0 + p;
        const float* c = x + (((size_t)b * TT + (t + 1)) * NN + n) * 3;
        const float cx = c[0], cy = c[1], cz = c[2];
        const float s1 = cx * cx + cy * cy + cz * cz;

        // distances: candidate j = i*64 + lane (stride-1 across lanes -> no
        // LDS bank conflicts). Same formula as jax: (s1+s2) - 2*dot.
        float dist[16];
        #pragma unroll
        for (int i = 0; i < 16; ++i) {
            const int j = i * 64 + lane;
            const float dt = cx * x2x[j] + cy * x2y[j] + cz * x2z[j];
            dist[i] = (s1 + s2[j]) - 2.0f * dt;
        }

        // 20x wave-wide argmin with lowest-index tie-break
        int nb[KNN];
        #pragma unroll
        for (int k = 0; k < KNN; ++k) {
            float bv = dist[0];
            int bi = 0;
            #pragma unroll
            for (int i = 1; i < 16; ++i) {
                if (dist[i] < bv) { bv = dist[i]; bi = i; }  // strict < keeps lowest idx
            }
            int bj = bi * 64 + lane;
            #pragma unroll
            for (int off = 32; off >= 1; off >>= 1) {
                const float ov = __shfl_xor(bv, off, 64);
                const int   oj = __shfl_xor(bj, off, 64);
                if (ov < bv || (ov == bv && oj < bj)) { bv = ov; bj = oj; }
            }
            nb[k] = bj;
            #pragma unroll
            for (int i = 0; i < 16; ++i) {
                if (bj == i * 64 + lane) dist[i] = INFD;  // static index only
            }
        }

        // EdgeConv MLP: lane = channel. feat = (neigh, center - neigh)
        #pragma unroll
        for (int k = 0; k < KNN; ++k) {
            const int j = nb[k];                  // uniform -> LDS broadcast
            const float nx = x2x[j], ny = x2y[j], nz = x2z[j];
            float h = b1l;
            h = fmaf(nx, w0, h);
            h = fmaf(ny, w1, h);
            h = fmaf(nz, w2, h);
            h = fmaf(cx - nx, w3, h);
            h = fmaf(cy - ny, w4, h);
            h = fmaf(cz - nz, w5, h);
            h = fmaxf(h, 0.0f);                   // relu
            h = fmaf(h, scale, be1l);             // eval BN
            cmax = fmaxf(cmax, h);                // per-edge clamp folded into max
        }
    }

    // combine 4 waves in LDS, then one global atomic per channel per block.
    // cmax >= 0 so float bits order like uints.
    atomicMax(&smax[lane], __float_as_uint(cmax));
    __syncthreads();
    if (tid < HH) {
        unsigned* dst = (unsigned*)(acc + ((size_t)b * 448 + t * 64 + tid));
        atomicMax(dst, smax[tid]);
    }
}

// ---------------------------------------------------------------------------
// Kernel B: MLP head, one block (512 threads) per batch row.
// ---------------------------------------------------------------------------
__global__ __launch_bounds__(512) void head_kernel(
    const float* __restrict__ acc,  // [B,448]
    const float* __restrict__ Wa, const float* __restrict__ ba,
    const float* __restrict__ ga, const float* __restrict__ bea,
    const float* __restrict__ Wb, const float* __restrict__ bb,
    const float* __restrict__ gb, const float* __restrict__ beb,
    const float* __restrict__ Wc, const float* __restrict__ bc,
    float* __restrict__ out)        // [B,CLS]
{
    __shared__ float s0[448];
    __shared__ float h1[512];
    __shared__ float h2[256];
    __shared__ float lg[CLS];
    __shared__ float red[2];

    const int b   = blockIdx.x;
    const int tid = threadIdx.x;
    const float inv = 1.0f / sqrtf(1.0f + kEPS);

    if (tid < 448) s0[tid] = acc[(size_t)b * 448 + tid];
    __syncthreads();

    {   // layer a: 448 -> 512
        float s = ba[tid];
        for (int d = 0; d < 448; ++d) s = fmaf(s0[d], Wa[d * 512 + tid], s);
        s = fmaxf(s, 0.0f);
        h1[tid] = fmaf(s, ga[tid] * inv, bea[tid]);
    }
    __syncthreads();
    if (tid < 256) {  // layer b: 512 -> 256
        float s = bb[tid];
        for (int d = 0; d < 512; ++d) s = fmaf(h1[d], Wb[d * 256 + tid], s);
        s = fmaxf(s, 0.0f);
        h2[tid] = fmaf(s, gb[tid] * inv, beb[tid]);
    }
    __syncthreads();
    if (tid < CLS) {  // logits: 256 -> 14
        float s = bc[tid];
        for (int d = 0; d < 256; ++d) s = fmaf(h2[d], Wc[d * CLS + tid], s);
        lg[tid] = s;
    }
    __syncthreads();
    if (tid == 0) {   // log_softmax over 14 classes
        float m = lg[0];
        for (int j = 1; j < CLS; ++j) m = fmaxf(m, lg[j]);
        float ssum = 0.0f;
        for (int j = 0; j < CLS; ++j) ssum += expf(lg[j] - m);
        red[0] = m;
        red[1] = logf(ssum);
    }
    __syncthreads();
    if (tid < CLS) out[(size_t)b * CLS + tid] = lg[tid] - red[0] - red[1];
}

extern "C" void kernel_launch(void* const* d_in, const int* in_sizes, int n_in,
                              void* d_out, int out_size, void* d_ws, size_t ws_size,
                              hipStream_t stream) {
    const float* x   = (const float*)d_in[0];
    // d_in[1] = batch (int64) — unused by the computation
    const float* W1  = (const float*)d_in[2];
    const float* b1  = (const float*)d_in[3];
    const float* g1  = (const float*)d_in[4];
    const float* be1 = (const float*)d_in[5];
    const float* Wa  = (const float*)d_in[6];
    const float* ba  = (const float*)d_in[7];
    const float* ga  = (const float*)d_in[8];
    const float* bea = (const float*)d_in[9];
    const float* Wb  = (const float*)d_in[10];
    const float* bb  = (const float*)d_in[11];
    const float* gb  = (const float*)d_in[12];
    const float* beb = (const float*)d_in[13];
    const float* Wc  = (const float*)d_in[14];
    const float* bc  = (const float*)d_in[15];
    float* out = (float*)d_out;
    float* acc = (float*)d_ws;      // [B,448] accumulator

    hipMemsetAsync(acc, 0, (size_t)BB * 448 * sizeof(float), stream);

    dim3 grid(16, BB, 7);           // 16 chunks x 32 batches x 7 timesteps
    knn_edge_kernel<<<grid, 256, 0, stream>>>(x, W1, b1, g1, be1, acc);
    head_kernel<<<BB, 512, 0, stream>>>(acc, Wa, ba, ga, bea,
                                        Wb, bb, gb, beb, Wc, bc, out);
}

// Round 2
// 510.748 us; speedup vs baseline: 2.6638x; 2.6638x over previous
//
#include <hip/hip_runtime.h>

#define BB 32
#define TT 8
#define NN 1024
#define KNN 20
#define HH 64
#define CLS 14

__device__ __constant__ float kEPS = 1e-5f;

// ascending bitonic sort of one value per lane across the 64-lane wave
__device__ __forceinline__ float bitonic64_f32(float v, int lane) {
    #pragma unroll
    for (int k = 2; k <= 64; k <<= 1) {
        #pragma unroll
        for (int j = k >> 1; j >= 1; j >>= 1) {
            const float o = __shfl_xor(v, j, 64);
            const bool keepmin = (((lane & k) == 0) == ((lane & j) == 0));
            v = keepmin ? fminf(v, o) : fmaxf(v, o);
        }
    }
    return v;
}

__device__ __forceinline__ unsigned long long bitonic64_u64(unsigned long long v, int lane) {
    #pragma unroll
    for (int k = 2; k <= 64; k <<= 1) {
        #pragma unroll
        for (int j = k >> 1; j >= 1; j >>= 1) {
            const unsigned long long o = __shfl_xor(v, j, 64);
            const bool keepmin = (((lane & k) == 0) == ((lane & j) == 0));
            const bool lt = (v < o);
            const unsigned long long mn = lt ? v : o;
            const unsigned long long mx = lt ? o : v;
            v = keepmin ? mn : mx;
        }
    }
    return v;
}

// ---------------------------------------------------------------------------
// Kernel A: per (t, b, 64-point chunk). One wave handles 16 query points.
// Selection per point: per-lane min (15 ops) -> bitonic sort of 64 lane-mins
// -> pivot = 20th smallest lane-min (provably >= true 20th-smallest distance)
// -> ballot-compact survivors (~24 expected) to LDS as (flip(dist)<<32|idx)
// -> one 64-wide bitonic u64 sort -> lanes 0..19 = exact jax top-20 set.
// Then EdgeConv MLP with lane = channel, clamp at 0 folded into running max,
// uint atomicMax into acc.
// ---------------------------------------------------------------------------
__global__ __launch_bounds__(256) void knn_edge_kernel(
    const float* __restrict__ x,    // [B,T,N,3]
    const float* __restrict__ W1,   // [6,H]
    const float* __restrict__ b1,   // [H]
    const float* __restrict__ g1,   // [H]
    const float* __restrict__ be1,  // [H]
    float* __restrict__ acc)        // [B, 7*H], zero-initialized
{
    __shared__ float4 pts[NN];                      // x, y, z, |p|^2
    __shared__ unsigned long long keybuf[4][64];    // per-wave survivor keys
    __shared__ unsigned nbuf[4][KNN];               // per-wave neighbor indices
    __shared__ unsigned smax[HH];

    const int chunk = blockIdx.x;   // 0..15
    const int b     = blockIdx.y;   // 0..31
    const int t     = blockIdx.z;   // 0..6: xyz2 = x[:,t], xyz1 = x[:,t+1]

    const int tid  = threadIdx.x;
    const int lane = tid & 63;
    const int wave = tid >> 6;

    // stage xyz2[b] and squared norms as float4
    for (int i = tid; i < NN; i += 256) {
        const float* p = x + (((size_t)b * TT + t) * NN + i) * 3;
        const float px = p[0], py = p[1], pz = p[2];
        pts[i] = make_float4(px, py, pz, px * px + py * py + pz * pz);
    }
    if (tid < HH) smax[tid] = 0u;
    __syncthreads();

    // per-lane (= per-channel) MLP constants
    const float w0 = W1[0 * HH + lane], w1 = W1[1 * HH + lane],
                w2 = W1[2 * HH + lane], w3 = W1[3 * HH + lane],
                w4 = W1[4 * HH + lane], w5 = W1[5 * HH + lane];
    const float b1l   = b1[lane];
    const float scale = g1[lane] / sqrtf(1.0f + kEPS);
    const float be1l  = be1[lane];

    const unsigned long long below = (1ull << lane) - 1ull;
    float cmax = 0.0f;   // final clamp-at-0 folded in

    const int n0 = chunk * 64 + wave * 16;
    for (int p = 0; p < 16; ++p) {
        const int n = n0 + p;
        const float* c = x + (((size_t)b * TT + (t + 1)) * NN + n) * 3;
        const float cx = c[0], cy = c[1], cz = c[2];
        const float s1 = cx * cx + cy * cy + cz * cz;

        // distances: candidate j = i*64 + lane. Same formula as jax.
        float d[16];
        #pragma unroll
        for (int i = 0; i < 16; ++i) {
            const float4 q = pts[i * 64 + lane];
            const float dt = cx * q.x + cy * q.y + cz * q.z;
            d[i] = (s1 + q.w) - 2.0f * dt;
        }

        // pivot = 20th smallest of the 64 per-lane mins (upper bound on d(20))
        float m = d[0];
        #pragma unroll
        for (int i = 1; i < 16; ++i) m = fminf(m, d[i]);
        m = bitonic64_f32(m, lane);
        const float pivot = __shfl(m, 19, 64);

        // ballot-compact survivors (d <= pivot) into per-wave LDS key buffer
        int base = 0;
        #pragma unroll
        for (int i = 0; i < 16; ++i) {
            const bool pred = (d[i] <= pivot);
            const unsigned long long mk = __ballot(pred);
            if (pred) {
                const int pos = base + (int)__popcll(mk & below);
                if (pos < 64) {
                    unsigned u = __float_as_uint(d[i]);
                    u ^= ((unsigned)((int)u >> 31)) | 0x80000000u;  // order-preserving flip
                    keybuf[wave][pos] =
                        ((unsigned long long)u << 32) | (unsigned)(i * 64 + lane);
                }
            }
            base += (int)__popcll(mk);
        }

        if (base <= 64) {
            // exact top-20 = 20 smallest survivor keys (lexicographic = jax ties)
            unsigned long long kv = (lane < base) ? keybuf[wave][lane] : ~0ull;
            kv = bitonic64_u64(kv, lane);
            if (lane < KNN) nbuf[wave][lane] = (unsigned)kv & 1023u;
        } else {
            // pathological tie storm: fall back to exact iterative extraction
            for (int kk = 0; kk < KNN; ++kk) {
                float bv = d[0];
                int bi = 0;
                #pragma unroll
                for (int i = 1; i < 16; ++i) {
                    if (d[i] < bv) { bv = d[i]; bi = i; }
                }
                int bj = bi * 64 + lane;
                #pragma unroll
                for (int off = 32; off >= 1; off >>= 1) {
                    const float ov = __shfl_xor(bv, off, 64);
                    const int   oj = __shfl_xor(bj, off, 64);
                    if (ov < bv || (ov == bv && oj < bj)) { bv = ov; bj = oj; }
                }
                if (lane == 0) nbuf[wave][kk] = (unsigned)bj;
                #pragma unroll
                for (int i = 0; i < 16; ++i) {
                    if (bj == i * 64 + lane) d[i] = 3.0e38f;
                }
            }
        }

        // EdgeConv MLP: lane = channel. feat = (neigh, center - neigh)
        #pragma unroll
        for (int kk = 0; kk < KNN; ++kk) {
            const int j = (int)nbuf[wave][kk];     // uniform -> LDS broadcast
            const float4 q = pts[j];
            float h = b1l;
            h = fmaf(q.x, w0, h);
            h = fmaf(q.y, w1, h);
            h = fmaf(q.z, w2, h);
            h = fmaf(cx - q.x, w3, h);
            h = fmaf(cy - q.y, w4, h);
            h = fmaf(cz - q.z, w5, h);
            h = fmaxf(h, 0.0f);                    // relu
            h = fmaf(h, scale, be1l);              // eval BN
            cmax = fmaxf(cmax, h);                 // per-edge clamp folded into max
        }
    }

    // combine 4 waves in LDS, then one global atomic per channel per block.
    atomicMax(&smax[lane], __float_as_uint(cmax));
    __syncthreads();
    if (tid < HH) {
        unsigned* dst = (unsigned*)(acc + ((size_t)b * 448 + t * 64 + tid));
        atomicMax(dst, smax[tid]);
    }
}

// ---------------------------------------------------------------------------
// Kernel B: MLP head, one block (512 threads) per batch row.
// ---------------------------------------------------------------------------
__global__ __launch_bounds__(512) void head_kernel(
    const float* __restrict__ acc,  // [B,448]
    const float* __restrict__ Wa, const float* __restrict__ ba,
    const float* __restrict__ ga, const float* __restrict__ bea,
    const float* __restrict__ Wb, const float* __restrict__ bb,
    const float* __restrict__ gb, const float* __restrict__ beb,
    const float* __restrict__ Wc, const float* __restrict__ bc,
    float* __restrict__ out)        // [B,CLS]
{
    __shared__ float s0[448];
    __shared__ float h1[512];
    __shared__ float h2[256];
    __shared__ float lg[CLS];
    __shared__ float red[2];

    const int b   = blockIdx.x;
    const int tid = threadIdx.x;
    const float inv = 1.0f / sqrtf(1.0f + kEPS);

    if (tid < 448) s0[tid] = acc[(size_t)b * 448 + tid];
    __syncthreads();

    {   // layer a: 448 -> 512
        float s = ba[tid];
        for (int d = 0; d < 448; ++d) s = fmaf(s0[d], Wa[d * 512 + tid], s);
        s = fmaxf(s, 0.0f);
        h1[tid] = fmaf(s, ga[tid] * inv, bea[tid]);
    }
    __syncthreads();
    if (tid < 256) {  // layer b: 512 -> 256
        float s = bb[tid];
        for (int d = 0; d < 512; ++d) s = fmaf(h1[d], Wb[d * 256 + tid], s);
        s = fmaxf(s, 0.0f);
        h2[tid] = fmaf(s, gb[tid] * inv, beb[tid]);
    }
    __syncthreads();
    if (tid < CLS) {  // logits: 256 -> 14
        float s = bc[tid];
        for (int d = 0; d < 256; ++d) s = fmaf(h2[d], Wc[d * CLS + tid], s);
        lg[tid] = s;
    }
    __syncthreads();
    if (tid == 0) {   // log_softmax over 14 classes
        float m = lg[0];
        for (int j = 1; j < CLS; ++j) m = fmaxf(m, lg[j]);
        float ssum = 0.0f;
        for (int j = 0; j < CLS; ++j) ssum += expf(lg[j] - m);
        red[0] = m;
        red[1] = logf(ssum);
    }
    __syncthreads();
    if (tid < CLS) out[(size_t)b * CLS + tid] = lg[tid] - red[0] - red[1];
}

extern "C" void kernel_launch(void* const* d_in, const int* in_sizes, int n_in,
                              void* d_out, int out_size, void* d_ws, size_t ws_size,
                              hipStream_t stream) {
    const float* x   = (const float*)d_in[0];
    // d_in[1] = batch (int64) — unused by the computation
    const float* W1  = (const float*)d_in[2];
    const float* b1  = (const float*)d_in[3];
    const float* g1  = (const float*)d_in[4];
    const float* be1 = (const float*)d_in[5];
    const float* Wa  = (const float*)d_in[6];
    const float* ba  = (const float*)d_in[7];
    const float* ga  = (const float*)d_in[8];
    const float* bea = (const float*)d_in[9];
    const float* Wb  = (const float*)d_in[10];
    const float* bb  = (const float*)d_in[11];
    const float* gb  = (const float*)d_in[12];
    const float* beb = (const float*)d_in[13];
    const float* Wc  = (const float*)d_in[14];
    const float* bc  = (const float*)d_in[15];
    float* out = (float*)d_out;
    float* acc = (float*)d_ws;      // [B,448] accumulator

    hipMemsetAsync(acc, 0, (size_t)BB * 448 * sizeof(float), stream);

    dim3 grid(16, BB, 7);           // 16 chunks x 32 batches x 7 timesteps
    knn_edge_kernel<<<grid, 256, 0, stream>>>(x, W1, b1, g1, be1, acc);
    head_kernel<<<BB, 512, 0, stream>>>(acc, Wa, ba, ga, bea,
                                        Wb, bb, gb, beb, Wc, bc, out);
}